// Round 13
// baseline (174.882 us; speedup 1.0000x reference)
//
#include <hip/hip_runtime.h>
#include <hip/hip_bf16.h>

typedef short bf16x8 __attribute__((ext_vector_type(8)));
typedef float f32x4 __attribute__((ext_vector_type(4)));
typedef unsigned short u16;
typedef unsigned int u32;

__device__ __forceinline__ u16 f2b(float v) {
    u32 u = __float_as_uint(v);
    u += 0x7fff + ((u >> 16) & 1);   // round-to-nearest-even
    return (u16)(u >> 16);
}

__device__ __forceinline__ u32 cvtpk(float lo, float hi) {
    u32 r;
    asm("v_cvt_pk_bf16_f32 %0, %1, %2" : "=v"(r) : "v"(lo), "v"(hi));
    return r;
}

__device__ __forceinline__ void gload16(const void* g, void* l) {
    __builtin_amdgcn_global_load_lds(
        (const __attribute__((address_space(1))) u32*)g,
        (__attribute__((address_space(3))) u32*)l, 16, 0, 0);
}

// ---------------- prep kernels ----------------
// wt[n*K + k] = w[k*N + n]  (f32 -> bf16)
__global__ void cast_transpose(const float* __restrict__ w, u16* __restrict__ wt, int N, int K) {
    int i = blockIdx.x * blockDim.x + threadIdx.x;
    if (i >= N * K) return;
    int n = i / K, k = i - n * K;
    wt[i] = f2b(w[(size_t)k * N + n]);
}

// rpb[h][i][j] = table[rpi[i][j]*6 + h]
__global__ void rpb_gather(const int* __restrict__ rpi, const float* __restrict__ table,
                           float* __restrict__ rpb) {
    int ij = blockIdx.x * blockDim.x + threadIdx.x;  // 65536
    int idx = rpi[ij];
#pragma unroll
    for (int h = 0; h < 6; ++h) rpb[h * 65536 + ij] = table[idx * 6 + h];
}

// ---------------- QKV GEMM: x_f32[65536][192] x Bt[576][192]^T ----------------
// BM=128 (512 blocks), A read DIRECTLY from f32 x (cvt_pk in kernel), wave owns
// 16 rows in registers; 9 N-tiles of 64 cols, double-buffered async B staging.
// Epilogue writes K and V^T PRE-SWIZZLED for attn's LDS read pattern.
__global__ __launch_bounds__(512, 4) void qkv_gemm(const float* __restrict__ A,
                                                   const u16* __restrict__ Bt,
                                                   const float* __restrict__ bias,
                                                   u16* __restrict__ qb, u16* __restrict__ kb,
                                                   u16* __restrict__ vtb, float qscale) {
    __shared__ u16 lsB[2][64 * 192];
    const int m0 = blockIdx.x * 128;
    const int tid = threadIdx.x;
    const int l = tid & 63, wv = tid >> 6;
    const int lr = l & 15, lg = l >> 4;

    bf16x8 areg[6];
    {
        const float* arow = A + (size_t)(m0 + wv * 16 + lr) * 192;
#pragma unroll
        for (int ks = 0; ks < 6; ++ks) {
            float4 a0 = *(const float4*)(arow + ks * 32 + lg * 8);
            float4 a1 = *(const float4*)(arow + ks * 32 + lg * 8 + 4);
            union { u32 u[4]; bf16x8 v; } pk;
            pk.u[0] = cvtpk(a0.x, a0.y);
            pk.u[1] = cvtpk(a0.z, a0.w);
            pk.u[2] = cvtpk(a1.x, a1.y);
            pk.u[3] = cvtpk(a1.z, a1.w);
            areg[ks] = pk.v;
        }
    }

#define STAGE_B(tile, buf)                                                      \
    {                                                                           \
        const u16* src = Bt + (size_t)(tile) * 64 * 192;                        \
        for (int c = tid; c < 1536; c += 512) {                                 \
            int r = c / 24, mc = c - r * 24;                                    \
            int gsw = (mc & ~7) | ((mc ^ r) & 7);                               \
            gload16(src + (r * 24 + gsw) * 8, &lsB[buf][c * 8]);                \
        }                                                                       \
    }
    STAGE_B(0, 0);
    __syncthreads();

    const int wq = m0 >> 8;
    const int ibase = (blockIdx.x & 1) * 128 + wv * 16 + lg * 4;

    for (int n0 = 0; n0 < 9; ++n0) {
        const int cur = n0 & 1;
        if (n0 < 8) STAGE_B(n0 + 1, cur ^ 1);

        f32x4 acc[4] = {};
#pragma unroll
        for (int ks = 0; ks < 6; ++ks) {
            int cidx = ks * 4 + lg;
            int csw = (cidx & ~7) | ((cidx ^ lr) & 7);
#pragma unroll
            for (int bn = 0; bn < 4; ++bn) {
                bf16x8 b = *(const bf16x8*)&lsB[cur][(bn * 16 + lr) * 192 + csw * 8];
                acc[bn] = __builtin_amdgcn_mfma_f32_16x16x32_bf16(areg[ks], b, acc[bn], 0, 0, 0);
            }
        }
        __syncthreads();

        const int mat = n0 / 3;
        const int base = (n0 - mat * 3) * 64;
#pragma unroll
        for (int bn = 0; bn < 4; ++bn)
#pragma unroll
            for (int j = 0; j < 4; ++j) {
                int ii = ibase + j;
                int rem = base + bn * 16 + lr;
                int hh = rem >> 5, dd = rem & 31;
                size_t w6h = (size_t)(wq * 6 + hh);
                float v = acc[bn][j] + bias[mat * 192 + rem];
                if (mat == 0) {
                    qb[(w6h * 256 + ii) * 32 + dd] = f2b(v * qscale);
                } else if (mat == 1) {
                    int m2 = ((dd >> 3) ^ (ii >> 1)) & 3;
                    kb[w6h * 8192 + ii * 32 + (dd & 7) + m2 * 8] = f2b(v);
                } else {
                    int cc = ii >> 5, col = ii & 31;
                    int m2 = ((col >> 3) ^ (dd >> 1)) & 3;
                    vtb[w6h * 8192 + cc * 1024 + dd * 32 + (col & 7) + m2 * 8] = f2b(v);
                }
            }
    }
}

// ---------------- proj GEMM: C[M][192] = A[M][192] * Bt[192][192]^T ----------------
__global__ __launch_bounds__(512) void proj_gemm(const u16* __restrict__ A,
                                                 const u16* __restrict__ Bt,
                                                 const float* __restrict__ bias,
                                                 float* __restrict__ out) {
    __shared__ u16 lsA[128 * 200];
    __shared__ u16 lsB[64 * 200];
    const int m0 = blockIdx.x * 128;
    const int n0 = blockIdx.y * 64;
    const int tid = threadIdx.x;

    for (int c = tid; c < 128 * 24; c += 512) {
        int r = c / 24, cc = c % 24;
        *(uint4*)&lsA[r * 200 + cc * 8] = *(const uint4*)(A + (size_t)(m0 + r) * 192 + cc * 8);
    }
    for (int c = tid; c < 64 * 24; c += 512) {
        int r = c / 24, cc = c % 24;
        *(uint4*)&lsB[r * 200 + cc * 8] = *(const uint4*)(Bt + (size_t)(n0 + r) * 192 + cc * 8);
    }
    __syncthreads();

    const int l = tid & 63, wv = tid >> 6;
    const int wm = wv >> 1, wn = wv & 1;
    const int lr = l & 15, lg = l >> 4;

    f32x4 acc[2][2] = {};
#pragma unroll
    for (int ks = 0; ks < 6; ++ks) {
        bf16x8 a[2], b[2];
#pragma unroll
        for (int i = 0; i < 2; ++i)
            a[i] = *(const bf16x8*)&lsA[(wm * 32 + i * 16 + lr) * 200 + ks * 32 + lg * 8];
#pragma unroll
        for (int i = 0; i < 2; ++i)
            b[i] = *(const bf16x8*)&lsB[(wn * 32 + i * 16 + lr) * 200 + ks * 32 + lg * 8];
#pragma unroll
        for (int m = 0; m < 2; ++m)
#pragma unroll
            for (int n = 0; n < 2; ++n)
                acc[m][n] = __builtin_amdgcn_mfma_f32_16x16x32_bf16(a[m], b[n], acc[m][n], 0, 0, 0);
    }

#pragma unroll
    for (int m = 0; m < 2; ++m)
#pragma unroll
        for (int n = 0; n < 2; ++n)
#pragma unroll
            for (int j = 0; j < 4; ++j) {
                int gr = m0 + wm * 32 + m * 16 + lg * 4 + j;
                int gc = n0 + wn * 32 + n * 16 + lr;
                out[(size_t)gr * 192 + gc] = acc[m][n][j] + bias[gc];
            }
}

// ---------------- attention ----------------
// r12 structure (passed; conflicts=0) + explicit 2-chunk software pipeline:
// per iteration process kv chunks 2p and 2p+1 with SEPARATE register sets and
// SPLIT accumulators (oA/oB, sumA/sumB) -> 2 independent QK->exp->butterfly->PV
// chains in flight per wave (r12 was chain-serial: VGPR 64, MfmaUtil 6%).
// block = (window, q-half), 8 waves x 16 q-rows, 6-head loop, double-buffered
// K/V staging, whole-head mask burst. S^T layout: lane owns q = lr.
__global__ __launch_bounds__(512, 4) void attn_k(const u16* __restrict__ qb,
                                                 const u16* __restrict__ kb,
                                                 const u16* __restrict__ vtb,
                                                 const float* __restrict__ rpb,
                                                 const float* __restrict__ mask,
                                                 u16* __restrict__ out) {
    __shared__ u16 lk[2][8192];    // K head rows (swizzled content, linear layout)
    __shared__ u16 lvt[2][8192];   // V^T head, chunk-major (swizzled content)

    const int bid = blockIdx.x;
    const int xcd = bid & 7, idx = bid >> 3;
    const int w = xcd * 32 + (idx >> 1), half = idx & 1;
    const int tid = threadIdx.x;
    const int l = tid & 63, wv = tid >> 6;
    const int lr = l & 15, lg = l >> 4;
    const int qrow = half * 128 + wv * 16 + lr;

#define STAGE_KV(hh, buf)                                                        \
    {                                                                            \
        const u16* ks = kb + (size_t)(w * 6 + (hh)) * 8192;                      \
        const u16* vs = vtb + (size_t)(w * 6 + (hh)) * 8192;                     \
        for (int c = tid; c < 1024; c += 512) {                                  \
            gload16(ks + c * 8, &lk[buf][c * 8]);                                \
            gload16(vs + c * 8, &lvt[buf][c * 8]);                               \
        }                                                                        \
    }

    STAGE_KV(0, 0);
    bf16x8 bq_n = *(const bf16x8*)(qb + ((size_t)(w * 6 + 0) * 256 + qrow) * 32 + lg * 8);
    __syncthreads();  // head 0 staged

    const float* mrow = mask + (size_t)w * 65536 + (size_t)qrow * 256;
    const int koff = lr * 32 + (lg ^ ((lr >> 1) & 3)) * 8;  // swizzled read offset
    const bool lo2 = (lg < 2);
    const bool ev = ((lg & 1) == 0);

// exp over a chunk's 8 values (s0,s1) with mask regs m0_,m1_ and rpb f4 b0_,b1_
#define EXP8(s0, s1, m0_, m1_, b0_, b1_, sacc)                                   \
    s0[0] = __expf(s0[0] + m0_.x + b0_.x);                                       \
    s0[1] = __expf(s0[1] + m0_.y + b0_.y);                                       \
    s0[2] = __expf(s0[2] + m0_.z + b0_.z);                                       \
    s0[3] = __expf(s0[3] + m0_.w + b0_.w);                                       \
    s1[0] = __expf(s1[0] + m1_.x + b1_.x);                                       \
    s1[1] = __expf(s1[1] + m1_.y + b1_.y);                                       \
    s1[2] = __expf(s1[2] + m1_.z + b1_.z);                                       \
    s1[3] = __expf(s1[3] + m1_.w + b1_.w);                                       \
    sacc += ((s0[0] + s0[1]) + (s0[2] + s0[3])) + ((s1[0] + s1[1]) + (s1[2] + s1[3]));

// butterfly transpose of packed P (4 words in, A-frag out)
#define BFLY(s0, s1, apv)                                                        \
    {                                                                            \
        u32 aw = cvtpk(s0[0], s0[1]);                                            \
        u32 bw = cvtpk(s0[2], s0[3]);                                            \
        u32 cw = cvtpk(s1[0], s1[1]);                                            \
        u32 dw = cvtpk(s1[2], s1[3]);                                            \
        u32 r1a = (u32)__shfl_xor((int)(lo2 ? cw : aw), 32);                     \
        u32 r1b = (u32)__shfl_xor((int)(lo2 ? dw : bw), 32);                     \
        u32 w0 = lo2 ? aw : r1a;                                                 \
        u32 w1 = lo2 ? bw : r1b;                                                 \
        u32 w2 = lo2 ? r1a : cw;                                                 \
        u32 w3 = lo2 ? r1b : dw;                                                 \
        u32 r2a = (u32)__shfl_xor((int)(ev ? w2 : w0), 16);                      \
        u32 r2b = (u32)__shfl_xor((int)(ev ? w3 : w1), 16);                      \
        union { u32 u[4]; bf16x8 v; } pk_;                                       \
        pk_.u[0] = ev ? w0 : r2a;                                                \
        pk_.u[1] = ev ? w1 : r2b;                                                \
        pk_.u[2] = ev ? r2a : w2;                                                \
        pk_.u[3] = ev ? r2b : w3;                                                \
        apv = pk_.v;                                                             \
    }

    for (int h = 0; h < 6; ++h) {
        const int cur = h & 1, nxt = cur ^ 1;
        if (h < 5) STAGE_KV(h + 1, nxt);
        bf16x8 bq = bq_n;
        if (h < 5)
            bq_n = *(const bf16x8*)(qb + ((size_t)(w * 6 + h + 1) * 256 + qrow) * 32 + lg * 8);

        const float* brow = rpb + (size_t)h * 65536 + (size_t)qrow * 256;

        // burst: issue the whole head's mask loads (16 x float4, 8-deep MLP)
        float4 mv[16];
#pragma unroll
        for (int c = 0; c < 8; ++c) {
            mv[2 * c]     = *(const float4*)(mrow + c * 32 + lg * 4);
            mv[2 * c + 1] = *(const float4*)(mrow + c * 32 + 16 + lg * 4);
        }

        const f32x4 zero = {0.f, 0.f, 0.f, 0.f};
        f32x4 oA[2] = {}, oB[2] = {};
        float sumA = 0.f, sumB = 0.f;

#pragma unroll
        for (int p = 0; p < 4; ++p) {
            const int ca = 2 * p, cb = 2 * p + 1;
            // QK^T both chunks (4 independent MFMAs)
            bf16x8 akA0 = *(const bf16x8*)&lk[cur][(2 * ca) * 512 + koff];
            bf16x8 akA1 = *(const bf16x8*)&lk[cur][(2 * ca + 1) * 512 + koff];
            bf16x8 akB0 = *(const bf16x8*)&lk[cur][(2 * cb) * 512 + koff];
            bf16x8 akB1 = *(const bf16x8*)&lk[cur][(2 * cb + 1) * 512 + koff];
            f32x4 sA0 = __builtin_amdgcn_mfma_f32_16x16x32_bf16(akA0, bq, zero, 0, 0, 0);
            f32x4 sA1 = __builtin_amdgcn_mfma_f32_16x16x32_bf16(akA1, bq, zero, 0, 0, 0);
            f32x4 sB0 = __builtin_amdgcn_mfma_f32_16x16x32_bf16(akB0, bq, zero, 0, 0, 0);
            f32x4 sB1 = __builtin_amdgcn_mfma_f32_16x16x32_bf16(akB1, bq, zero, 0, 0, 0);

            float4 bvA0 = *(const float4*)(brow + ca * 32 + lg * 4);
            float4 bvA1 = *(const float4*)(brow + ca * 32 + 16 + lg * 4);
            float4 bvB0 = *(const float4*)(brow + cb * 32 + lg * 4);
            float4 bvB1 = *(const float4*)(brow + cb * 32 + 16 + lg * 4);

            EXP8(sA0, sA1, mv[2 * ca], mv[2 * ca + 1], bvA0, bvA1, sumA);
            EXP8(sB0, sB1, mv[2 * cb], mv[2 * cb + 1], bvB0, bvB1, sumB);

            bf16x8 apA, apB;
            BFLY(sA0, sA1, apA);
            BFLY(sB0, sB1, apB);

            bf16x8 vA0 = *(const bf16x8*)&lvt[cur][ca * 1024 + koff];
            bf16x8 vA1 = *(const bf16x8*)&lvt[cur][ca * 1024 + 512 + koff];
            bf16x8 vB0 = *(const bf16x8*)&lvt[cur][cb * 1024 + koff];
            bf16x8 vB1 = *(const bf16x8*)&lvt[cur][cb * 1024 + 512 + koff];
            oA[0] = __builtin_amdgcn_mfma_f32_16x16x32_bf16(apA, vA0, oA[0], 0, 0, 0);
            oA[1] = __builtin_amdgcn_mfma_f32_16x16x32_bf16(apA, vA1, oA[1], 0, 0, 0);
            oB[0] = __builtin_amdgcn_mfma_f32_16x16x32_bf16(apB, vB0, oB[0], 0, 0, 0);
            oB[1] = __builtin_amdgcn_mfma_f32_16x16x32_bf16(apB, vB1, oB[1], 0, 0, 0);
        }

        float sum = sumA + sumB;
        sum += __shfl_xor(sum, 16);
        sum += __shfl_xor(sum, 32);
        float rinv[4];
#pragma unroll
        for (int j = 0; j < 4; ++j) rinv[j] = __builtin_amdgcn_rcpf(__shfl(sum, lg * 4 + j));
#pragma unroll
        for (int dt = 0; dt < 2; ++dt)
#pragma unroll
            for (int j = 0; j < 4; ++j) {
                int i = half * 128 + wv * 16 + lg * 4 + j;
                out[((size_t)(w * 256 + i)) * 192 + h * 32 + dt * 16 + lr] =
                    f2b((oA[dt][j] + oB[dt][j]) * rinv[j]);
            }
        __syncthreads();  // next-head staging landed; cur buffers free
    }
}

extern "C" void kernel_launch(void* const* d_in, const int* in_sizes, int n_in,
                              void* d_out, int out_size, void* d_ws, size_t ws_size,
                              hipStream_t stream) {
    const float* x      = (const float*)d_in[0];
    const int*   rpi    = (const int*)d_in[1];
    const float* mask   = (const float*)d_in[2];
    const float* qkv_w  = (const float*)d_in[3];
    const float* qkv_b  = (const float*)d_in[4];
    const float* proj_w = (const float*)d_in[5];
    const float* proj_b = (const float*)d_in[6];
    const float* table  = (const float*)d_in[7];

    char* p = (char*)d_ws;
    u16* ob   = (u16*)p;  p += (size_t)65536 * 192 * 2;  // attn output bf16
    u16* qb   = (u16*)p;  p += (size_t)65536 * 192 * 2;  // Q  [w][h][i][d] bf16 (pre-scaled)
    u16* kb   = (u16*)p;  p += (size_t)65536 * 192 * 2;  // K  [w][h][i][d'] bf16 (swizzled)
    u16* vtb  = (u16*)p;  p += (size_t)65536 * 192 * 2;  // V^T [w][h][c][d][col'] (swizzled)
    u16* wtq  = (u16*)p;  p += (size_t)576 * 192 * 2;    // qkv_w^T bf16
    u16* wtp  = (u16*)p;  p += (size_t)192 * 192 * 2;    // proj_w^T bf16
    float* rpb = (float*)p; p += (size_t)6 * 65536 * 4;  // [6][256][256]

    hipLaunchKernelGGL(cast_transpose, dim3((576 * 192 + 255) / 256), dim3(256), 0, stream,
                       qkv_w, wtq, 576, 192);
    hipLaunchKernelGGL(cast_transpose, dim3((192 * 192 + 255) / 256), dim3(256), 0, stream,
                       proj_w, wtp, 192, 192);
    hipLaunchKernelGGL(rpb_gather, dim3(256), dim3(256), 0, stream, rpi, table, rpb);

    const float qscale = 0.17677669529663687f;  // 1/sqrt(32)
    hipLaunchKernelGGL(qkv_gemm, dim3(512), dim3(512), 0, stream,
                       x, wtq, qkv_b, qb, kb, vtb, qscale);
    hipLaunchKernelGGL(attn_k, dim3(512), dim3(512), 0, stream, qb, kb, vtb, rpb, mask, ob);
    hipLaunchKernelGGL(proj_gemm, dim3(512, 3), dim3(512), 0, stream,
                       ob, wtp, proj_b, (float*)d_out);
}

// Round 14
// 134.311 us; speedup vs baseline: 1.3021x; 1.3021x over previous
//
#include <hip/hip_runtime.h>
#include <hip/hip_bf16.h>

typedef short bf16x8 __attribute__((ext_vector_type(8)));
typedef float f32x4 __attribute__((ext_vector_type(4)));
typedef unsigned short u16;
typedef unsigned int u32;

__device__ __forceinline__ u16 f2b(float v) {
    u32 u = __float_as_uint(v);
    u += 0x7fff + ((u >> 16) & 1);   // round-to-nearest-even
    return (u16)(u >> 16);
}

__device__ __forceinline__ u32 cvtpk(float lo, float hi) {
    u32 r;
    asm("v_cvt_pk_bf16_f32 %0, %1, %2" : "=v"(r) : "v"(lo), "v"(hi));
    return r;
}

__device__ __forceinline__ void gload16(const void* g, void* l) {
    __builtin_amdgcn_global_load_lds(
        (const __attribute__((address_space(1))) u32*)g,
        (__attribute__((address_space(3))) u32*)l, 16, 0, 0);
}

// ---------------- prep kernels ----------------
// wt[n*K + k] = w[k*N + n]  (f32 -> bf16)
__global__ void cast_transpose(const float* __restrict__ w, u16* __restrict__ wt, int N, int K) {
    int i = blockIdx.x * blockDim.x + threadIdx.x;
    if (i >= N * K) return;
    int n = i / K, k = i - n * K;
    wt[i] = f2b(w[(size_t)k * N + n]);
}

// rpb[h][i][j] = table[rpi[i][j]*6 + h]
__global__ void rpb_gather(const int* __restrict__ rpi, const float* __restrict__ table,
                           float* __restrict__ rpb) {
    int ij = blockIdx.x * blockDim.x + threadIdx.x;  // 65536
    int idx = rpi[ij];
#pragma unroll
    for (int h = 0; h < 6; ++h) rpb[h * 65536 + ij] = table[idx * 6 + h];
}

// ---------------- QKV GEMM: x_f32[65536][192] x Bt[576][192]^T ----------------
// BM=128 (512 blocks), A read DIRECTLY from f32 x (cvt_pk in kernel), wave owns
// 16 rows in registers; 9 N-tiles of 64 cols, double-buffered async B staging.
// Epilogue writes K and V^T PRE-SWIZZLED for attn's LDS read pattern.
__global__ __launch_bounds__(512, 4) void qkv_gemm(const float* __restrict__ A,
                                                   const u16* __restrict__ Bt,
                                                   const float* __restrict__ bias,
                                                   u16* __restrict__ qb, u16* __restrict__ kb,
                                                   u16* __restrict__ vtb, float qscale) {
    __shared__ u16 lsB[2][64 * 192];
    const int m0 = blockIdx.x * 128;
    const int tid = threadIdx.x;
    const int l = tid & 63, wv = tid >> 6;
    const int lr = l & 15, lg = l >> 4;

    bf16x8 areg[6];
    {
        const float* arow = A + (size_t)(m0 + wv * 16 + lr) * 192;
#pragma unroll
        for (int ks = 0; ks < 6; ++ks) {
            float4 a0 = *(const float4*)(arow + ks * 32 + lg * 8);
            float4 a1 = *(const float4*)(arow + ks * 32 + lg * 8 + 4);
            union { u32 u[4]; bf16x8 v; } pk;
            pk.u[0] = cvtpk(a0.x, a0.y);
            pk.u[1] = cvtpk(a0.z, a0.w);
            pk.u[2] = cvtpk(a1.x, a1.y);
            pk.u[3] = cvtpk(a1.z, a1.w);
            areg[ks] = pk.v;
        }
    }

#define STAGE_B(tile, buf)                                                      \
    {                                                                           \
        const u16* src = Bt + (size_t)(tile) * 64 * 192;                        \
        for (int c = tid; c < 1536; c += 512) {                                 \
            int r = c / 24, mc = c - r * 24;                                    \
            int gsw = (mc & ~7) | ((mc ^ r) & 7);                               \
            gload16(src + (r * 24 + gsw) * 8, &lsB[buf][c * 8]);                \
        }                                                                       \
    }
    STAGE_B(0, 0);
    __syncthreads();

    const int wq = m0 >> 8;
    const int ibase = (blockIdx.x & 1) * 128 + wv * 16 + lg * 4;

    for (int n0 = 0; n0 < 9; ++n0) {
        const int cur = n0 & 1;
        if (n0 < 8) STAGE_B(n0 + 1, cur ^ 1);

        f32x4 acc[4] = {};
#pragma unroll
        for (int ks = 0; ks < 6; ++ks) {
            int cidx = ks * 4 + lg;
            int csw = (cidx & ~7) | ((cidx ^ lr) & 7);
#pragma unroll
            for (int bn = 0; bn < 4; ++bn) {
                bf16x8 b = *(const bf16x8*)&lsB[cur][(bn * 16 + lr) * 192 + csw * 8];
                acc[bn] = __builtin_amdgcn_mfma_f32_16x16x32_bf16(areg[ks], b, acc[bn], 0, 0, 0);
            }
        }
        __syncthreads();

        const int mat = n0 / 3;
        const int base = (n0 - mat * 3) * 64;
#pragma unroll
        for (int bn = 0; bn < 4; ++bn)
#pragma unroll
            for (int j = 0; j < 4; ++j) {
                int ii = ibase + j;
                int rem = base + bn * 16 + lr;
                int hh = rem >> 5, dd = rem & 31;
                size_t w6h = (size_t)(wq * 6 + hh);
                float v = acc[bn][j] + bias[mat * 192 + rem];
                if (mat == 0) {
                    qb[(w6h * 256 + ii) * 32 + dd] = f2b(v * qscale);
                } else if (mat == 1) {
                    int m2 = ((dd >> 3) ^ (ii >> 1)) & 3;
                    kb[w6h * 8192 + ii * 32 + (dd & 7) + m2 * 8] = f2b(v);
                } else {
                    int cc = ii >> 5, col = ii & 31;
                    int m2 = ((col >> 3) ^ (dd >> 1)) & 3;
                    vtb[w6h * 8192 + cc * 1024 + dd * 32 + (col & 7) + m2 * 8] = f2b(v);
                }
            }
    }
}

// ---------------- proj GEMM: out[65536][192] = ob[65536][192] x wtp[192][192]^T ----
// r14: qkv_gemm style — whole 192x192 B panel staged ONCE in LDS (72 KB,
// swizzled), A held in registers (read once, not re-staged 3x), 3 N-tile loop,
// single barrier. BM=128, 512 blocks, 8 waves (wave owns 16 rows).
__global__ __launch_bounds__(512, 4) void proj_gemm(const u16* __restrict__ A,
                                                    const u16* __restrict__ Bt,
                                                    const float* __restrict__ bias,
                                                    float* __restrict__ out) {
    __shared__ u16 lsB[192 * 192];
    const int m0 = blockIdx.x * 128;
    const int tid = threadIdx.x;
    const int l = tid & 63, wv = tid >> 6;
    const int lr = l & 15, lg = l >> 4;

    // stage whole B panel (192 rows x 24 chunks), same swizzle as qkv's lsB
    for (int c = tid; c < 4608; c += 512) {
        int r = c / 24, mc = c - r * 24;
        int gsw = (mc & ~7) | ((mc ^ r) & 7);
        gload16(Bt + (r * 24 + gsw) * 8, &lsB[c * 8]);
    }

    bf16x8 areg[6];
    {
        const u16* arow = A + (size_t)(m0 + wv * 16 + lr) * 192;
#pragma unroll
        for (int ks = 0; ks < 6; ++ks)
            areg[ks] = *(const bf16x8*)(arow + ks * 32 + lg * 8);
    }
    __syncthreads();

#pragma unroll
    for (int t = 0; t < 3; ++t) {
        f32x4 acc[4] = {};
#pragma unroll
        for (int ks = 0; ks < 6; ++ks) {
            int cidx = ks * 4 + lg;
            int csw = (cidx & ~7) | ((cidx ^ lr) & 7);
#pragma unroll
            for (int bn = 0; bn < 4; ++bn) {
                bf16x8 b = *(const bf16x8*)&lsB[(t * 64 + bn * 16 + lr) * 192 + csw * 8];
                acc[bn] = __builtin_amdgcn_mfma_f32_16x16x32_bf16(areg[ks], b, acc[bn], 0, 0, 0);
            }
        }
#pragma unroll
        for (int bn = 0; bn < 4; ++bn)
#pragma unroll
            for (int j = 0; j < 4; ++j) {
                int gr = m0 + wv * 16 + lg * 4 + j;
                int gc = t * 64 + bn * 16 + lr;
                out[(size_t)gr * 192 + gc] = acc[bn][j] + bias[gc];
            }
    }
}

// ---------------- attention ----------------
// r12 structure EXACTLY (passed, 81 us, conflicts=0, compiler-friendly at
// VGPR=64) + s_setprio(1) around MFMA pairs (T5; waves are unsynchronized
// across the chunk loop -> scheduler has role diversity to arbitrate).
// Lesson r7/r13: hipcc pins 64 VGPRs here; manual ILP widening only spills.
__global__ __launch_bounds__(512, 4) void attn_k(const u16* __restrict__ qb,
                                                 const u16* __restrict__ kb,
                                                 const u16* __restrict__ vtb,
                                                 const float* __restrict__ rpb,
                                                 const float* __restrict__ mask,
                                                 u16* __restrict__ out) {
    __shared__ u16 lk[2][8192];    // K head rows (swizzled content, linear layout)
    __shared__ u16 lvt[2][8192];   // V^T head, chunk-major (swizzled content)

    const int bid = blockIdx.x;
    const int xcd = bid & 7, idx = bid >> 3;
    const int w = xcd * 32 + (idx >> 1), half = idx & 1;
    const int tid = threadIdx.x;
    const int l = tid & 63, wv = tid >> 6;
    const int lr = l & 15, lg = l >> 4;
    const int qrow = half * 128 + wv * 16 + lr;

#define STAGE_KV(hh, buf)                                                        \
    {                                                                            \
        const u16* ks = kb + (size_t)(w * 6 + (hh)) * 8192;                      \
        const u16* vs = vtb + (size_t)(w * 6 + (hh)) * 8192;                     \
        for (int c = tid; c < 1024; c += 512) {                                  \
            gload16(ks + c * 8, &lk[buf][c * 8]);                                \
            gload16(vs + c * 8, &lvt[buf][c * 8]);                               \
        }                                                                        \
    }

    STAGE_KV(0, 0);
    bf16x8 bq_n = *(const bf16x8*)(qb + ((size_t)(w * 6 + 0) * 256 + qrow) * 32 + lg * 8);
    __syncthreads();  // head 0 staged

    const float* mrow = mask + (size_t)w * 65536 + (size_t)qrow * 256;
    const int koff = lr * 32 + (lg ^ ((lr >> 1) & 3)) * 8;  // swizzled read offset
    const bool lo2 = (lg < 2);
    const bool ev = ((lg & 1) == 0);

    for (int h = 0; h < 6; ++h) {
        const int cur = h & 1, nxt = cur ^ 1;
        if (h < 5) STAGE_KV(h + 1, nxt);
        bf16x8 bq = bq_n;
        if (h < 5)
            bq_n = *(const bf16x8*)(qb + ((size_t)(w * 6 + h + 1) * 256 + qrow) * 32 + lg * 8);

        const float* brow = rpb + (size_t)h * 65536 + (size_t)qrow * 256;

        // burst: issue the whole head's mask loads (16 x float4, 8-deep MLP)
        float4 mv[16];
#pragma unroll
        for (int c = 0; c < 8; ++c) {
            mv[2 * c]     = *(const float4*)(mrow + c * 32 + lg * 4);
            mv[2 * c + 1] = *(const float4*)(mrow + c * 32 + 16 + lg * 4);
        }

        const f32x4 zero = {0.f, 0.f, 0.f, 0.f};
        f32x4 o[2] = {};
        float sum = 0.f;

#pragma unroll
        for (int c = 0; c < 8; ++c) {
            // QK^T for 32 kv cols
            bf16x8 ak0 = *(const bf16x8*)&lk[cur][(2 * c) * 512 + koff];
            bf16x8 ak1 = *(const bf16x8*)&lk[cur][(2 * c + 1) * 512 + koff];
            __builtin_amdgcn_s_setprio(1);
            f32x4 s0 = __builtin_amdgcn_mfma_f32_16x16x32_bf16(ak0, bq, zero, 0, 0, 0);
            f32x4 s1 = __builtin_amdgcn_mfma_f32_16x16x32_bf16(ak1, bq, zero, 0, 0, 0);
            __builtin_amdgcn_s_setprio(0);

            // rpb in-loop (L2-hot, 1.5 MB total), mask from burst registers
            float4 bv0 = *(const float4*)(brow + c * 32 + lg * 4);
            float4 bv1 = *(const float4*)(brow + c * 32 + 16 + lg * 4);

            s0[0] = __expf(s0[0] + mv[2 * c].x + bv0.x);
            s0[1] = __expf(s0[1] + mv[2 * c].y + bv0.y);
            s0[2] = __expf(s0[2] + mv[2 * c].z + bv0.z);
            s0[3] = __expf(s0[3] + mv[2 * c].w + bv0.w);
            s1[0] = __expf(s1[0] + mv[2 * c + 1].x + bv1.x);
            s1[1] = __expf(s1[1] + mv[2 * c + 1].y + bv1.y);
            s1[2] = __expf(s1[2] + mv[2 * c + 1].z + bv1.z);
            s1[3] = __expf(s1[3] + mv[2 * c + 1].w + bv1.w);
            sum += ((s0[0] + s0[1]) + (s0[2] + s0[3])) + ((s1[0] + s1[1]) + (s1[2] + s1[3]));

            // pack P and transpose in-register (2-round butterfly)
            u32 aw = cvtpk(s0[0], s0[1]);
            u32 bw = cvtpk(s0[2], s0[3]);
            u32 cw = cvtpk(s1[0], s1[1]);
            u32 dw = cvtpk(s1[2], s1[3]);

            u32 r1a = (u32)__shfl_xor((int)(lo2 ? cw : aw), 32);
            u32 r1b = (u32)__shfl_xor((int)(lo2 ? dw : bw), 32);
            u32 w0 = lo2 ? aw : r1a;
            u32 w1 = lo2 ? bw : r1b;
            u32 w2 = lo2 ? r1a : cw;
            u32 w3 = lo2 ? r1b : dw;
            u32 r2a = (u32)__shfl_xor((int)(ev ? w2 : w0), 16);
            u32 r2b = (u32)__shfl_xor((int)(ev ? w3 : w1), 16);
            u32 f0 = ev ? w0 : r2a;
            u32 f1 = ev ? w1 : r2b;
            u32 f2 = ev ? r2a : w2;
            u32 f3 = ev ? r2b : w3;

            union { u32 u[4]; bf16x8 v; } pk;
            pk.u[0] = f0; pk.u[1] = f1; pk.u[2] = f2; pk.u[3] = f3;
            bf16x8 ap = pk.v;   // A-frag: P[q=lr][kv = lg*8 .. lg*8+7]

            bf16x8 v0 = *(const bf16x8*)&lvt[cur][c * 1024 + koff];
            bf16x8 v1 = *(const bf16x8*)&lvt[cur][c * 1024 + 512 + koff];
            __builtin_amdgcn_s_setprio(1);
            o[0] = __builtin_amdgcn_mfma_f32_16x16x32_bf16(ap, v0, o[0], 0, 0, 0);
            o[1] = __builtin_amdgcn_mfma_f32_16x16x32_bf16(ap, v1, o[1], 0, 0, 0);
            __builtin_amdgcn_s_setprio(0);
        }

        sum += __shfl_xor(sum, 16);
        sum += __shfl_xor(sum, 32);
        float rinv[4];
#pragma unroll
        for (int j = 0; j < 4; ++j) rinv[j] = __builtin_amdgcn_rcpf(__shfl(sum, lg * 4 + j));
#pragma unroll
        for (int dt = 0; dt < 2; ++dt)
#pragma unroll
            for (int j = 0; j < 4; ++j) {
                int i = half * 128 + wv * 16 + lg * 4 + j;
                out[((size_t)(w * 256 + i)) * 192 + h * 32 + dt * 16 + lr] =
                    f2b(o[dt][j] * rinv[j]);
            }
        __syncthreads();  // next-head staging landed; cur buffers free
    }
}

extern "C" void kernel_launch(void* const* d_in, const int* in_sizes, int n_in,
                              void* d_out, int out_size, void* d_ws, size_t ws_size,
                              hipStream_t stream) {
    const float* x      = (const float*)d_in[0];
    const int*   rpi    = (const int*)d_in[1];
    const float* mask   = (const float*)d_in[2];
    const float* qkv_w  = (const float*)d_in[3];
    const float* qkv_b  = (const float*)d_in[4];
    const float* proj_w = (const float*)d_in[5];
    const float* proj_b = (const float*)d_in[6];
    const float* table  = (const float*)d_in[7];

    char* p = (char*)d_ws;
    u16* ob   = (u16*)p;  p += (size_t)65536 * 192 * 2;  // attn output bf16
    u16* qb   = (u16*)p;  p += (size_t)65536 * 192 * 2;  // Q  [w][h][i][d] bf16 (pre-scaled)
    u16* kb   = (u16*)p;  p += (size_t)65536 * 192 * 2;  // K  [w][h][i][d'] bf16 (swizzled)
    u16* vtb  = (u16*)p;  p += (size_t)65536 * 192 * 2;  // V^T [w][h][c][d][col'] (swizzled)
    u16* wtq  = (u16*)p;  p += (size_t)576 * 192 * 2;    // qkv_w^T bf16
    u16* wtp  = (u16*)p;  p += (size_t)192 * 192 * 2;    // proj_w^T bf16
    float* rpb = (float*)p; p += (size_t)6 * 65536 * 4;  // [6][256][256]

    hipLaunchKernelGGL(cast_transpose, dim3((576 * 192 + 255) / 256), dim3(256), 0, stream,
                       qkv_w, wtq, 576, 192);
    hipLaunchKernelGGL(cast_transpose, dim3((192 * 192 + 255) / 256), dim3(256), 0, stream,
                       proj_w, wtp, 192, 192);
    hipLaunchKernelGGL(rpb_gather, dim3(256), dim3(256), 0, stream, rpi, table, rpb);

    const float qscale = 0.17677669529663687f;  // 1/sqrt(32)
    hipLaunchKernelGGL(qkv_gemm, dim3(512), dim3(512), 0, stream,
                       x, wtq, qkv_b, qb, kb, vtb, qscale);
    hipLaunchKernelGGL(attn_k, dim3(512), dim3(512), 0, stream, qb, kb, vtb, rpb, mask, ob);
    hipLaunchKernelGGL(proj_gemm, dim3(512), dim3(512), 0, stream,
                       ob, wtp, proj_b, (float*)d_out);
}